// Round 11
// baseline (251.081 us; speedup 1.0000x reference)
//
#include <hip/hip_runtime.h>

#define Hdim 128
#define Wdim 128
#define Cdim 64
#define HW   (Hdim * Wdim)
#define NPIX (4 * HW)     // 65536
#define NBLK (NPIX / 64)  // 1024 offset blocks, 64 pixels each
#define NBLK2 (NPIX / 32) // 2048 deform blocks, 32 pixels each
#define NXCD 8
#define Hp 130            // padded dims
#define HWp (Hp * Hp)     // 16900

// XCD-aware bijective swizzle (nwg % 8 == 0): consecutive logical blocks
// (which share image rows -> x reuse) land on the SAME XCD's L2.  Both
// kernels cover pixels [q*NPIX/8, (q+1)*NPIX/8) on XCD q -> producer and
// consumer of xt/geo stay L2-local.
__device__ __forceinline__ int xcd_swizzle(int bid, int nblk) {
    return (bid % NXCD) * (nblk / NXCD) + bid / NXCD;
}

// geo layout: [group = pixel>>3][k:9][i:8 px][8 dwords {w0..w3, i0..i3}]
// -> one 8-pixel group's geometry = 576 contiguous dwords (2304 B).

// ---------------------------------------------------------------------------
// Kernel A: fused {NCHW->padded-NHWC transpose} + {offset conv dw3x3 + pw
// 64->18} + {sampling geometry}.  (unchanged from R10)
// ---------------------------------------------------------------------------
__global__ __launch_bounds__(512) void offset_geo_kernel(
    const float* __restrict__ x,     // (B, C, H, W)
    const float* __restrict__ p_dw,  // (C, 1, 3, 3)
    const float* __restrict__ p_pw,  // (18, C, 1, 1)
    float* __restrict__ xt,          // (B, 130, 130, C) padded NHWC
    float* __restrict__ geo)         // (8192, 9, 8, 8) dwords
{
    __shared__ float part[8][18][64];   // 36.8 KB; part[0] reused as sum

    int lane = threadIdx.x & 63;
    int g    = threadIdx.x >> 6;
    int blk  = xcd_swizzle(blockIdx.x, NBLK);
    int pix0 = blk * 64;
    int pix  = pix0 + lane;
    int w = pix & (Wdim - 1);
    int h = (pix >> 7) & (Hdim - 1);
    int b = pix >> 14;

    // --- zero the pad ring of xt (2064 ring positions x 16 float4) -------
    {
        int gid = blockIdx.x * 512 + threadIdx.x;   // raw id: blocks 0..64
        if (gid < 2064 * 16) {
            int rp  = gid >> 4, sub = gid & 15;
            int img = rp / 516, pos = rp - img * 516;
            int i, j;
            if (pos < 130)      { i = 0;   j = pos; }
            else if (pos < 260) { i = 129; j = pos - 130; }
            else { int p2 = pos - 260; i = 1 + (p2 >> 1); j = (p2 & 1) ? 129 : 0; }
            float4* dst = (float4*)(xt + ((size_t)img * HWp + i * Hp + j) * Cdim);
            dst[sub] = make_float4(0.f, 0.f, 0.f, 0.f);
        }
    }

    // --- depthwise 3x3: masks/offsets hoisted out of the channel loop ----
    int   off9[9];
    float msk9[9];
#pragma unroll
    for (int dh = -1; dh <= 1; ++dh) {
#pragma unroll
        for (int dw = -1; dw <= 1; ++dw) {
            int tap = (dh + 1) * 3 + (dw + 1);
            int hh = h + dh, ww = w + dw;
            bool ok = (hh >= 0) & (hh < Hdim) & (ww >= 0) & (ww < Wdim);
            off9[tap] = ok ? hh * Wdim + ww : 0;
            msk9[tap] = ok ? 1.f : 0.f;
        }
    }

    float t[8], ctr[8];
#pragma unroll
    for (int i = 0; i < 8; ++i) {
        int c = g * 8 + i;              // wave-uniform
        const float* xb = x + (size_t)(b * Cdim + c) * HW;
        float s = 0.f;
#pragma unroll
        for (int tap = 0; tap < 9; ++tap) {
            float v = xb[off9[tap]] * msk9[tap];
            s += v * p_dw[c * 9 + tap];
        }
        t[i]   = s;
        ctr[i] = xb[h * Wdim + w];      // transpose source (center tap)
    }

    // --- transpose write: 8 contiguous floats per thread (32B chunks) ----
    {
        size_t ppos = ((size_t)b * HWp + (h + 1) * Hp + (w + 1)) * Cdim + g * 8;
        float4* cd = (float4*)(xt + ppos);
        cd[0] = make_float4(ctr[0], ctr[1], ctr[2], ctr[3]);
        cd[1] = make_float4(ctr[4], ctr[5], ctr[6], ctr[7]);
    }

    // --- pointwise 64->18 partials -> LDS ---------------------------------
#pragma unroll
    for (int j = 0; j < 18; ++j) {
        float s = 0.f;
#pragma unroll
        for (int i = 0; i < 8; ++i)
            s += p_pw[j * Cdim + g * 8 + i] * t[i];
        part[g][j][lane] = s;
    }
    __syncthreads();

    // reduce 8 partials into part[0]
#pragma unroll
    for (int it = 0; it < 3; ++it) {
        int idx = threadIdx.x + it * 512;
        if (idx < 18 * 64) {
            int j = idx >> 6;
            int p = idx & 63;
            float s = part[0][j][p];
#pragma unroll
            for (int q = 1; q < 8; ++q) s += part[q][j][p];
            part[0][j][p] = s;
        }
    }
    __syncthreads();

    // --- geometry pass: reference formulas verbatim on the padded grid ---
#pragma unroll
    for (int it = 0; it < 2; ++it) {
        int idx = threadIdx.x + it * 512;
        if (idx < 9 * 64) {
            int k = idx >> 6;
            int p = idx & 63;
            int ppix = pix0 + p;
            int pw2 = ppix & (Wdim - 1);
            int ph2 = (ppix >> 7) & (Hdim - 1);

            float px = (float)(ph2 + 1) + (float)(k / 3 - 1) + part[0][k][p];
            float py = (float)(pw2 + 1) + (float)(k % 3 - 1) + part[0][k + 9][p];

            float fx = floorf(px), fy = floorf(py);
            float ltx = fminf(fmaxf(fx, 0.f), 129.f);
            float lty = fminf(fmaxf(fy, 0.f), 129.f);
            float rbx = fminf(fmaxf(fx + 1.f, 0.f), 129.f);
            float rby = fminf(fmaxf(fy + 1.f, 0.f), 129.f);
            float pxc = fminf(fmaxf(px, 0.f), 129.f);
            float pyc = fminf(fmaxf(py, 0.f), 129.f);

            float glt = (1.f + ltx - pxc) * (1.f + lty - pyc);
            float grb = (1.f - rbx + pxc) * (1.f - rby + pyc);
            float glb = (1.f + ltx - pxc) * (1.f - rby + pyc);
            float grt = (1.f - rbx + pxc) * (1.f + lty - pyc);

            int ix0 = (int)ltx, iy0 = (int)lty, ix1 = (int)rbx, iy1 = (int)rby;

            // entry = (group*9 + k)*8 + i   (group = pixel>>3)
            size_t e = (((size_t)blk * 8 + (p >> 3)) * 9 + k) * 8 + (p & 7);
            float4* wdst = (float4*)(geo + e * 8);
            int4*   idst = (int4*)(geo + e * 8 + 4);
            *wdst = make_float4(glt, grb, glb, grt);
            *idst = make_int4(ix0 * Hp + iy0,   // lt
                              ix1 * Hp + iy1,   // rb
                              ix0 * Hp + iy1,   // lb
                              ix1 * Hp + iy0);  // rt
        }
    }
}

// ---------------------------------------------------------------------------
// Kernel B: deformable sampling + collapsed depthwise + pointwise.
// R11: 2048 blocks x 256 thr (32 px, 4 waves) -> 8 blocks/CU for load
// balance + latency hiding (R8-R10 ran exactly 4 blocks/CU, occupancy
// stuck at 36%).  Phase A unchanged per-wave (geo readlane broadcast,
// saddr gathers).  accs stride 66 (8B-aligned rows, 2-way-free banks) so
// phase B reads are ds_read_b64 float2 (R10: 64 scalar b32/thread).
// ---------------------------------------------------------------------------
__global__ __launch_bounds__(256, 8) void deform_kernel(
    const float* __restrict__ xt,    // (B, 130, 130, C) padded NHWC
    const float* __restrict__ c_dw,  // (C, 1, 3, 3)
    const float* __restrict__ c_pw,  // (C, C, 1, 1)
    const int* __restrict__ geo,     // (8192, 9, 8, 8) dwords
    float* __restrict__ out)         // (B, C, H, W)
{
    __shared__ float accs[32][66];   // [pixel][channel], 8.25 KB

    int lane = threadIdx.x & 63;
    int gu   = __builtin_amdgcn_readfirstlane(threadIdx.x >> 6);  // wave 0..3
    int blk  = xcd_swizzle(blockIdx.x, NBLK2);
    int pix0 = blk * 32;
    int b    = pix0 >> 14;           // block-uniform (32 | 16384)
    const float* xb = xt + (size_t)b * HWp * Cdim;

    // prefetch this wave's geometry: group = blk*4 + gu; 576 dwords -> 9 VGPRs
    int gv0, gv1, gv2, gv3, gv4, gv5, gv6, gv7, gv8;
    {
        const int* gb = geo + ((size_t)blk * 4 + gu) * 576 + lane;
        gv0 = gb[0];   gv1 = gb[64];  gv2 = gb[128];
        gv3 = gb[192]; gv4 = gb[256]; gv5 = gb[320];
        gv6 = gb[384]; gv7 = gb[448]; gv8 = gb[512];
    }
    // per-lane depthwise weights (lane = channel)
    float wk9[9];
#pragma unroll
    for (int k = 0; k < 9; ++k) wk9[k] = c_dw[lane * 9 + k];

#define GV(r) ((r)==0?gv0:(r)==1?gv1:(r)==2?gv2:(r)==3?gv3:(r)==4?gv4: \
               (r)==5?gv5:(r)==6?gv6:(r)==7?gv7:gv8)
#define RL(f) __builtin_amdgcn_readlane(GV((f) >> 6), (f) & 63)

    float acc[8];
#pragma unroll
    for (int i = 0; i < 8; ++i) acc[i] = 0.f;

#pragma unroll
    for (int k = 0; k < 9; ++k) {
#pragma unroll
        for (int i = 0; i < 8; ++i) {
            const int f = (k * 8 + i) * 8;
            float glt = __int_as_float(RL(f + 0));
            float grb = __int_as_float(RL(f + 1));
            float glb = __int_as_float(RL(f + 2));
            float grt = __int_as_float(RL(f + 3));
            const float* plt = xb + (size_t)RL(f + 4) * Cdim;
            const float* prb = xb + (size_t)RL(f + 5) * Cdim;
            const float* plb = xb + (size_t)RL(f + 6) * Cdim;
            const float* prt = xb + (size_t)RL(f + 7) * Cdim;
            float sv = glt * plt[lane] + grb * prb[lane]
                     + glb * plb[lane] + grt * prt[lane];
            acc[i] += wk9[k] * sv;
        }
    }
#undef RL
#undef GV

#pragma unroll
    for (int i = 0; i < 8; ++i) accs[gu * 8 + i][lane] = acc[i];
    __syncthreads();

    // Phase B: thread t -> pixel p = t&31, oc-group og = t>>5 (8 oc each).
    // accs rows are 8B-aligned (66*4=264) -> float2 LDS reads; lanes 0-31
    // and 32-63 read identical addresses (broadcast, free).
    int p  = threadIdx.x & 31;
    int og = threadIdx.x >> 5;
    int pix = pix0 + p;
    int hw  = pix & (HW - 1);

    float s[8];
#pragma unroll
    for (int i = 0; i < 8; ++i) s[i] = 0.f;

    for (int c0 = 0; c0 < Cdim; c0 += 8) {
        float2 x0 = *(const float2*)&accs[p][c0 + 0];
        float2 x1 = *(const float2*)&accs[p][c0 + 2];
        float2 x2 = *(const float2*)&accs[p][c0 + 4];
        float2 x3 = *(const float2*)&accs[p][c0 + 6];
#pragma unroll
        for (int i = 0; i < 8; ++i) {
            const float* wrow = c_pw + (og * 8 + i) * Cdim + c0;
            s[i] += wrow[0] * x0.x + wrow[1] * x0.y
                  + wrow[2] * x1.x + wrow[3] * x1.y
                  + wrow[4] * x2.x + wrow[5] * x2.y
                  + wrow[6] * x3.x + wrow[7] * x3.y;
        }
    }

    size_t obase = (size_t)b * Cdim * HW + hw;
#pragma unroll
    for (int i = 0; i < 8; ++i)
        out[obase + (size_t)(og * 8 + i) * HW] = s[i];
}

extern "C" void kernel_launch(void* const* d_in, const int* in_sizes, int n_in,
                              void* d_out, int out_size, void* d_ws, size_t ws_size,
                              hipStream_t stream) {
    const float* x    = (const float*)d_in[0];
    const float* p_dw = (const float*)d_in[1];
    const float* p_pw = (const float*)d_in[2];
    const float* c_dw = (const float*)d_in[3];
    const float* c_pw = (const float*)d_in[4];
    float* out = (float*)d_out;

    float* xt  = (float*)d_ws;                                  // 17.3 MB padded NHWC
    float* geo = (float*)((char*)d_ws + (size_t)4 * HWp * Cdim * 4);  // 18.9 MB

    offset_geo_kernel<<<dim3(NBLK), dim3(512), 0, stream>>>(x, p_dw, p_pw, xt, geo);
    deform_kernel<<<dim3(NBLK2), dim3(256), 0, stream>>>(xt, c_dw, c_pw, (const int*)geo, out);
}

// Round 12
// 115.496 us; speedup vs baseline: 2.1739x; 2.1739x over previous
//
#include <hip/hip_runtime.h>

#define Hdim 128
#define Wdim 128
#define Cdim 64
#define HW   (Hdim * Wdim)
#define NPIX (4 * HW)     // 65536
#define NBLK (NPIX / 64)  // 1024 offset blocks, 64 pixels each
#define NBLK2 (NPIX / 32) // 2048 deform blocks, 32 pixels each
#define NXCD 8
#define Hp 130            // padded dims
#define HWp (Hp * Hp)     // 16900

// XCD-aware bijective swizzle (nwg % 8 == 0): consecutive logical blocks
// (which share image rows -> x reuse) land on the SAME XCD's L2.  Both
// kernels cover pixels [q*NPIX/8, (q+1)*NPIX/8) on XCD q -> producer and
// consumer of xt/geo stay L2-local.
__device__ __forceinline__ int xcd_swizzle(int bid, int nblk) {
    return (bid % NXCD) * (nblk / NXCD) + bid / NXCD;
}

// geo layout: [group = pixel>>3][k:9][i:8 px][8 dwords {w0..w3, i0..i3}]
// -> one 8-pixel group's geometry = 576 contiguous dwords (2304 B).

// ---------------------------------------------------------------------------
// Kernel A: fused {NCHW->padded-NHWC transpose} + {offset conv dw3x3 + pw
// 64->18} + {sampling geometry}.  (unchanged from R10)
// ---------------------------------------------------------------------------
__global__ __launch_bounds__(512) void offset_geo_kernel(
    const float* __restrict__ x,     // (B, C, H, W)
    const float* __restrict__ p_dw,  // (C, 1, 3, 3)
    const float* __restrict__ p_pw,  // (18, C, 1, 1)
    float* __restrict__ xt,          // (B, 130, 130, C) padded NHWC
    float* __restrict__ geo)         // (8192, 9, 8, 8) dwords
{
    __shared__ float part[8][18][64];   // 36.8 KB; part[0] reused as sum

    int lane = threadIdx.x & 63;
    int g    = threadIdx.x >> 6;
    int blk  = xcd_swizzle(blockIdx.x, NBLK);
    int pix0 = blk * 64;
    int pix  = pix0 + lane;
    int w = pix & (Wdim - 1);
    int h = (pix >> 7) & (Hdim - 1);
    int b = pix >> 14;

    // --- zero the pad ring of xt (2064 ring positions x 16 float4) -------
    {
        int gid = blockIdx.x * 512 + threadIdx.x;   // raw id: blocks 0..64
        if (gid < 2064 * 16) {
            int rp  = gid >> 4, sub = gid & 15;
            int img = rp / 516, pos = rp - img * 516;
            int i, j;
            if (pos < 130)      { i = 0;   j = pos; }
            else if (pos < 260) { i = 129; j = pos - 130; }
            else { int p2 = pos - 260; i = 1 + (p2 >> 1); j = (p2 & 1) ? 129 : 0; }
            float4* dst = (float4*)(xt + ((size_t)img * HWp + i * Hp + j) * Cdim);
            dst[sub] = make_float4(0.f, 0.f, 0.f, 0.f);
        }
    }

    // --- depthwise 3x3: masks/offsets hoisted out of the channel loop ----
    int   off9[9];
    float msk9[9];
#pragma unroll
    for (int dh = -1; dh <= 1; ++dh) {
#pragma unroll
        for (int dw = -1; dw <= 1; ++dw) {
            int tap = (dh + 1) * 3 + (dw + 1);
            int hh = h + dh, ww = w + dw;
            bool ok = (hh >= 0) & (hh < Hdim) & (ww >= 0) & (ww < Wdim);
            off9[tap] = ok ? hh * Wdim + ww : 0;
            msk9[tap] = ok ? 1.f : 0.f;
        }
    }

    float t[8], ctr[8];
#pragma unroll
    for (int i = 0; i < 8; ++i) {
        int c = g * 8 + i;              // wave-uniform
        const float* xb = x + (size_t)(b * Cdim + c) * HW;
        float s = 0.f;
#pragma unroll
        for (int tap = 0; tap < 9; ++tap) {
            float v = xb[off9[tap]] * msk9[tap];
            s += v * p_dw[c * 9 + tap];
        }
        t[i]   = s;
        ctr[i] = xb[h * Wdim + w];      // transpose source (center tap)
    }

    // --- transpose write: 8 contiguous floats per thread (32B chunks) ----
    {
        size_t ppos = ((size_t)b * HWp + (h + 1) * Hp + (w + 1)) * Cdim + g * 8;
        float4* cd = (float4*)(xt + ppos);
        cd[0] = make_float4(ctr[0], ctr[1], ctr[2], ctr[3]);
        cd[1] = make_float4(ctr[4], ctr[5], ctr[6], ctr[7]);
    }

    // --- pointwise 64->18 partials -> LDS ---------------------------------
#pragma unroll
    for (int j = 0; j < 18; ++j) {
        float s = 0.f;
#pragma unroll
        for (int i = 0; i < 8; ++i)
            s += p_pw[j * Cdim + g * 8 + i] * t[i];
        part[g][j][lane] = s;
    }
    __syncthreads();

    // reduce 8 partials into part[0]
#pragma unroll
    for (int it = 0; it < 3; ++it) {
        int idx = threadIdx.x + it * 512;
        if (idx < 18 * 64) {
            int j = idx >> 6;
            int p = idx & 63;
            float s = part[0][j][p];
#pragma unroll
            for (int q = 1; q < 8; ++q) s += part[q][j][p];
            part[0][j][p] = s;
        }
    }
    __syncthreads();

    // --- geometry pass: reference formulas verbatim on the padded grid ---
#pragma unroll
    for (int it = 0; it < 2; ++it) {
        int idx = threadIdx.x + it * 512;
        if (idx < 9 * 64) {
            int k = idx >> 6;
            int p = idx & 63;
            int ppix = pix0 + p;
            int pw2 = ppix & (Wdim - 1);
            int ph2 = (ppix >> 7) & (Hdim - 1);

            float px = (float)(ph2 + 1) + (float)(k / 3 - 1) + part[0][k][p];
            float py = (float)(pw2 + 1) + (float)(k % 3 - 1) + part[0][k + 9][p];

            float fx = floorf(px), fy = floorf(py);
            float ltx = fminf(fmaxf(fx, 0.f), 129.f);
            float lty = fminf(fmaxf(fy, 0.f), 129.f);
            float rbx = fminf(fmaxf(fx + 1.f, 0.f), 129.f);
            float rby = fminf(fmaxf(fy + 1.f, 0.f), 129.f);
            float pxc = fminf(fmaxf(px, 0.f), 129.f);
            float pyc = fminf(fmaxf(py, 0.f), 129.f);

            float glt = (1.f + ltx - pxc) * (1.f + lty - pyc);
            float grb = (1.f - rbx + pxc) * (1.f - rby + pyc);
            float glb = (1.f + ltx - pxc) * (1.f - rby + pyc);
            float grt = (1.f - rbx + pxc) * (1.f + lty - pyc);

            int ix0 = (int)ltx, iy0 = (int)lty, ix1 = (int)rbx, iy1 = (int)rby;

            // entry = (group*9 + k)*8 + i   (group = pixel>>3)
            size_t e = (((size_t)blk * 8 + (p >> 3)) * 9 + k) * 8 + (p & 7);
            float4* wdst = (float4*)(geo + e * 8);
            int4*   idst = (int4*)(geo + e * 8 + 4);
            *wdst = make_float4(glt, grb, glb, grt);
            *idst = make_int4(ix0 * Hp + iy0,   // lt
                              ix1 * Hp + iy1,   // rb
                              ix0 * Hp + iy1,   // lb
                              ix1 * Hp + iy0);  // rt
        }
    }
}

// ---------------------------------------------------------------------------
// Kernel B: deformable sampling + collapsed depthwise + pointwise.
// R12 = R11 structure (2048 blocks x 256 thr = 8 blocks/CU target) but NO
// min-waves launch-bounds arg: R11's (256,8) forced a 32-VGPR budget and
// spilled ~26 live VGPRs -> 381 MB scratch writes, 231us. Compiler settles
// ~56-64 VGPR naturally -> 8 waves/SIMD anyway, zero spill.
// ---------------------------------------------------------------------------
__global__ __launch_bounds__(256) void deform_kernel(
    const float* __restrict__ xt,    // (B, 130, 130, C) padded NHWC
    const float* __restrict__ c_dw,  // (C, 1, 3, 3)
    const float* __restrict__ c_pw,  // (C, C, 1, 1)
    const int* __restrict__ geo,     // (8192, 9, 8, 8) dwords
    float* __restrict__ out)         // (B, C, H, W)
{
    __shared__ float accs[32][66];   // [pixel][channel], 8.25 KB

    int lane = threadIdx.x & 63;
    int gu   = __builtin_amdgcn_readfirstlane(threadIdx.x >> 6);  // wave 0..3
    int blk  = xcd_swizzle(blockIdx.x, NBLK2);
    int pix0 = blk * 32;
    int b    = pix0 >> 14;           // block-uniform (32 | 16384)
    const float* xb = xt + (size_t)b * HWp * Cdim;

    // prefetch this wave's geometry: group = blk*4 + gu; 576 dwords -> 9 VGPRs
    int gv0, gv1, gv2, gv3, gv4, gv5, gv6, gv7, gv8;
    {
        const int* gb = geo + ((size_t)blk * 4 + gu) * 576 + lane;
        gv0 = gb[0];   gv1 = gb[64];  gv2 = gb[128];
        gv3 = gb[192]; gv4 = gb[256]; gv5 = gb[320];
        gv6 = gb[384]; gv7 = gb[448]; gv8 = gb[512];
    }
    // per-lane depthwise weights (lane = channel)
    float wk9[9];
#pragma unroll
    for (int k = 0; k < 9; ++k) wk9[k] = c_dw[lane * 9 + k];

#define GV(r) ((r)==0?gv0:(r)==1?gv1:(r)==2?gv2:(r)==3?gv3:(r)==4?gv4: \
               (r)==5?gv5:(r)==6?gv6:(r)==7?gv7:gv8)
#define RL(f) __builtin_amdgcn_readlane(GV((f) >> 6), (f) & 63)

    float acc[8];
#pragma unroll
    for (int i = 0; i < 8; ++i) acc[i] = 0.f;

#pragma unroll
    for (int k = 0; k < 9; ++k) {
#pragma unroll
        for (int i = 0; i < 8; ++i) {
            const int f = (k * 8 + i) * 8;
            float glt = __int_as_float(RL(f + 0));
            float grb = __int_as_float(RL(f + 1));
            float glb = __int_as_float(RL(f + 2));
            float grt = __int_as_float(RL(f + 3));
            const float* plt = xb + (size_t)RL(f + 4) * Cdim;
            const float* prb = xb + (size_t)RL(f + 5) * Cdim;
            const float* plb = xb + (size_t)RL(f + 6) * Cdim;
            const float* prt = xb + (size_t)RL(f + 7) * Cdim;
            float sv = glt * plt[lane] + grb * prb[lane]
                     + glb * plb[lane] + grt * prt[lane];
            acc[i] += wk9[k] * sv;
        }
    }
#undef RL
#undef GV

#pragma unroll
    for (int i = 0; i < 8; ++i) accs[gu * 8 + i][lane] = acc[i];
    __syncthreads();

    // Phase B: thread t -> pixel p = t&31, oc-group og = t>>5 (8 oc each).
    // accs rows are 8B-aligned (66*4=264) -> float2 LDS reads; lanes 0-31
    // and 32-63 read identical addresses (broadcast, free).
    int p  = threadIdx.x & 31;
    int og = threadIdx.x >> 5;
    int pix = pix0 + p;
    int hw  = pix & (HW - 1);

    float s[8];
#pragma unroll
    for (int i = 0; i < 8; ++i) s[i] = 0.f;

    for (int c0 = 0; c0 < Cdim; c0 += 8) {
        float2 x0 = *(const float2*)&accs[p][c0 + 0];
        float2 x1 = *(const float2*)&accs[p][c0 + 2];
        float2 x2 = *(const float2*)&accs[p][c0 + 4];
        float2 x3 = *(const float2*)&accs[p][c0 + 6];
#pragma unroll
        for (int i = 0; i < 8; ++i) {
            const float* wrow = c_pw + (og * 8 + i) * Cdim + c0;
            s[i] += wrow[0] * x0.x + wrow[1] * x0.y
                  + wrow[2] * x1.x + wrow[3] * x1.y
                  + wrow[4] * x2.x + wrow[5] * x2.y
                  + wrow[6] * x3.x + wrow[7] * x3.y;
        }
    }

    size_t obase = (size_t)b * Cdim * HW + hw;
#pragma unroll
    for (int i = 0; i < 8; ++i)
        out[obase + (size_t)(og * 8 + i) * HW] = s[i];
}

extern "C" void kernel_launch(void* const* d_in, const int* in_sizes, int n_in,
                              void* d_out, int out_size, void* d_ws, size_t ws_size,
                              hipStream_t stream) {
    const float* x    = (const float*)d_in[0];
    const float* p_dw = (const float*)d_in[1];
    const float* p_pw = (const float*)d_in[2];
    const float* c_dw = (const float*)d_in[3];
    const float* c_pw = (const float*)d_in[4];
    float* out = (float*)d_out;

    float* xt  = (float*)d_ws;                                  // 17.3 MB padded NHWC
    float* geo = (float*)((char*)d_ws + (size_t)4 * HWp * Cdim * 4);  // 18.9 MB

    offset_geo_kernel<<<dim3(NBLK), dim3(512), 0, stream>>>(x, p_dw, p_pw, xt, geo);
    deform_kernel<<<dim3(NBLK2), dim3(256), 0, stream>>>(xt, c_dw, c_pw, (const int*)geo, out);
}

// Round 13
// 80.753 us; speedup vs baseline: 3.1092x; 1.4302x over previous
//
#include <hip/hip_runtime.h>

#define Hdim 128
#define Wdim 128
#define Cdim 64
#define HW   (Hdim * Wdim)
#define NPIX (4 * HW)     // 65536
#define NBLK (NPIX / 64)  // 1024 offset blocks / tiles, 64 pixels each
#define NBLK2 256         // deform: persistent, 1 block/CU, 4 tiles each
#define NXCD 8
#define Hp 130            // padded dims
#define HWp (Hp * Hp)     // 16900

// XCD-aware bijective swizzle (nwg % 8 == 0). Producer (1024 blocks) and
// consumer (256 blocks x 4 tiles) both give XCD q the pixel range
// [q*8192, (q+1)*8192) -> xt/geo stay L2-local.
__device__ __forceinline__ int xcd_swizzle(int bid, int nblk) {
    return (bid % NXCD) * (nblk / NXCD) + bid / NXCD;
}

// geo layout: [group = pixel>>3][k:9][i:8 px][8 dwords {w0..w3, i0..i3}]

// ---------------------------------------------------------------------------
// Kernel A: fused {NCHW->padded-NHWC transpose} + {offset conv dw3x3 + pw
// 64->18} + {sampling geometry}.  (unchanged from R10)
// ---------------------------------------------------------------------------
__global__ __launch_bounds__(512) void offset_geo_kernel(
    const float* __restrict__ x,     // (B, C, H, W)
    const float* __restrict__ p_dw,  // (C, 1, 3, 3)
    const float* __restrict__ p_pw,  // (18, C, 1, 1)
    float* __restrict__ xt,          // (B, 130, 130, C) padded NHWC
    float* __restrict__ geo)         // (8192, 9, 8, 8) dwords
{
    __shared__ float part[8][18][64];   // 36.8 KB; part[0] reused as sum

    int lane = threadIdx.x & 63;
    int g    = threadIdx.x >> 6;
    int blk  = xcd_swizzle(blockIdx.x, NBLK);
    int pix0 = blk * 64;
    int pix  = pix0 + lane;
    int w = pix & (Wdim - 1);
    int h = (pix >> 7) & (Hdim - 1);
    int b = pix >> 14;

    // --- zero the pad ring of xt (2064 ring positions x 16 float4) -------
    {
        int gid = blockIdx.x * 512 + threadIdx.x;   // raw id: blocks 0..64
        if (gid < 2064 * 16) {
            int rp  = gid >> 4, sub = gid & 15;
            int img = rp / 516, pos = rp - img * 516;
            int i, j;
            if (pos < 130)      { i = 0;   j = pos; }
            else if (pos < 260) { i = 129; j = pos - 130; }
            else { int p2 = pos - 260; i = 1 + (p2 >> 1); j = (p2 & 1) ? 129 : 0; }
            float4* dst = (float4*)(xt + ((size_t)img * HWp + i * Hp + j) * Cdim);
            dst[sub] = make_float4(0.f, 0.f, 0.f, 0.f);
        }
    }

    // --- depthwise 3x3: masks/offsets hoisted out of the channel loop ----
    int   off9[9];
    float msk9[9];
#pragma unroll
    for (int dh = -1; dh <= 1; ++dh) {
#pragma unroll
        for (int dw = -1; dw <= 1; ++dw) {
            int tap = (dh + 1) * 3 + (dw + 1);
            int hh = h + dh, ww = w + dw;
            bool ok = (hh >= 0) & (hh < Hdim) & (ww >= 0) & (ww < Wdim);
            off9[tap] = ok ? hh * Wdim + ww : 0;
            msk9[tap] = ok ? 1.f : 0.f;
        }
    }

    float t[8], ctr[8];
#pragma unroll
    for (int i = 0; i < 8; ++i) {
        int c = g * 8 + i;              // wave-uniform
        const float* xb = x + (size_t)(b * Cdim + c) * HW;
        float s = 0.f;
#pragma unroll
        for (int tap = 0; tap < 9; ++tap) {
            float v = xb[off9[tap]] * msk9[tap];
            s += v * p_dw[c * 9 + tap];
        }
        t[i]   = s;
        ctr[i] = xb[h * Wdim + w];      // transpose source (center tap)
    }

    // --- transpose write: 8 contiguous floats per thread (32B chunks) ----
    {
        size_t ppos = ((size_t)b * HWp + (h + 1) * Hp + (w + 1)) * Cdim + g * 8;
        float4* cd = (float4*)(xt + ppos);
        cd[0] = make_float4(ctr[0], ctr[1], ctr[2], ctr[3]);
        cd[1] = make_float4(ctr[4], ctr[5], ctr[6], ctr[7]);
    }

    // --- pointwise 64->18 partials -> LDS ---------------------------------
#pragma unroll
    for (int j = 0; j < 18; ++j) {
        float s = 0.f;
#pragma unroll
        for (int i = 0; i < 8; ++i)
            s += p_pw[j * Cdim + g * 8 + i] * t[i];
        part[g][j][lane] = s;
    }
    __syncthreads();

    // reduce 8 partials into part[0]
#pragma unroll
    for (int it = 0; it < 3; ++it) {
        int idx = threadIdx.x + it * 512;
        if (idx < 18 * 64) {
            int j = idx >> 6;
            int p = idx & 63;
            float s = part[0][j][p];
#pragma unroll
            for (int q = 1; q < 8; ++q) s += part[q][j][p];
            part[0][j][p] = s;
        }
    }
    __syncthreads();

    // --- geometry pass: reference formulas verbatim on the padded grid ---
#pragma unroll
    for (int it = 0; it < 2; ++it) {
        int idx = threadIdx.x + it * 512;
        if (idx < 9 * 64) {
            int k = idx >> 6;
            int p = idx & 63;
            int ppix = pix0 + p;
            int pw2 = ppix & (Wdim - 1);
            int ph2 = (ppix >> 7) & (Hdim - 1);

            float px = (float)(ph2 + 1) + (float)(k / 3 - 1) + part[0][k][p];
            float py = (float)(pw2 + 1) + (float)(k % 3 - 1) + part[0][k + 9][p];

            float fx = floorf(px), fy = floorf(py);
            float ltx = fminf(fmaxf(fx, 0.f), 129.f);
            float lty = fminf(fmaxf(fy, 0.f), 129.f);
            float rbx = fminf(fmaxf(fx + 1.f, 0.f), 129.f);
            float rby = fminf(fmaxf(fy + 1.f, 0.f), 129.f);
            float pxc = fminf(fmaxf(px, 0.f), 129.f);
            float pyc = fminf(fmaxf(py, 0.f), 129.f);

            float glt = (1.f + ltx - pxc) * (1.f + lty - pyc);
            float grb = (1.f - rbx + pxc) * (1.f - rby + pyc);
            float glb = (1.f + ltx - pxc) * (1.f - rby + pyc);
            float grt = (1.f - rbx + pxc) * (1.f + lty - pyc);

            int ix0 = (int)ltx, iy0 = (int)lty, ix1 = (int)rbx, iy1 = (int)rby;

            // entry = (group*9 + k)*8 + i   (group = pixel>>3)
            size_t e = (((size_t)blk * 8 + (p >> 3)) * 9 + k) * 8 + (p & 7);
            float4* wdst = (float4*)(geo + e * 8);
            int4*   idst = (int4*)(geo + e * 8 + 4);
            *wdst = make_float4(glt, grb, glb, grt);
            *idst = make_int4(ix0 * Hp + iy0,   // lt
                              ix1 * Hp + iy1,   // rb
                              ix0 * Hp + iy1,   // lb
                              ix1 * Hp + iy0);  // rt
        }
    }
}

// ---------------------------------------------------------------------------
// Kernel B: deformable sampling + collapsed depthwise + pointwise.
// R13 = R10's exact per-tile structure (512 thr, wave-geo readlane broadcast,
// saddr gathers, scalar phase B) made PERSISTENT: 256 blocks (1/CU), each
// processes 4 consecutive tiles.  Per-CU per-k-step gather footprint drops
// 140 KB (4 blocks) -> 35 KB ~= L1, and adjacent tiles share rows, cutting
// L2->L1 refill traffic ~3-4x (R10's 43us wall = L1-miss fill at ~20B/cyc).
// ---------------------------------------------------------------------------
__global__ __launch_bounds__(512) void deform_kernel(
    const float* __restrict__ xt,    // (B, 130, 130, C) padded NHWC
    const float* __restrict__ c_dw,  // (C, 1, 3, 3)
    const float* __restrict__ c_pw,  // (C, C, 1, 1)
    const int* __restrict__ geo,     // (8192, 9, 8, 8) dwords
    float* __restrict__ out)         // (B, C, H, W)
{
    __shared__ float accs[64][65];   // [pixel][channel] padded, 16.6 KB

    int lane = threadIdx.x & 63;
    int gu   = __builtin_amdgcn_readfirstlane(threadIdx.x >> 6);
    int cub  = xcd_swizzle(blockIdx.x, NBLK2);   // 0..255

    // per-lane depthwise weights (lane = channel), loaded once
    float wk9[9];
#pragma unroll
    for (int k = 0; k < 9; ++k) wk9[k] = c_dw[lane * 9 + k];

    for (int t = 0; t < 4; ++t) {
        int tile = cub * 4 + t;
        int pix0 = tile * 64;
        int b    = pix0 >> 14;
        const float* xb = xt + (size_t)b * HWp * Cdim;

        // prefetch this wave's geometry: 576 dwords -> 9 VGPRs per lane
        int gv0, gv1, gv2, gv3, gv4, gv5, gv6, gv7, gv8;
        {
            const int* gb = geo + ((size_t)tile * 8 + gu) * 576 + lane;
            gv0 = gb[0];   gv1 = gb[64];  gv2 = gb[128];
            gv3 = gb[192]; gv4 = gb[256]; gv5 = gb[320];
            gv6 = gb[384]; gv7 = gb[448]; gv8 = gb[512];
        }

#define GV(r) ((r)==0?gv0:(r)==1?gv1:(r)==2?gv2:(r)==3?gv3:(r)==4?gv4: \
               (r)==5?gv5:(r)==6?gv6:(r)==7?gv7:gv8)
#define RL(f) __builtin_amdgcn_readlane(GV((f) >> 6), (f) & 63)

        float acc[8];
#pragma unroll
        for (int i = 0; i < 8; ++i) acc[i] = 0.f;

#pragma unroll
        for (int k = 0; k < 9; ++k) {
#pragma unroll
            for (int i = 0; i < 8; ++i) {
                const int f = (k * 8 + i) * 8;
                float glt = __int_as_float(RL(f + 0));
                float grb = __int_as_float(RL(f + 1));
                float glb = __int_as_float(RL(f + 2));
                float grt = __int_as_float(RL(f + 3));
                const float* plt = xb + (size_t)RL(f + 4) * Cdim;
                const float* prb = xb + (size_t)RL(f + 5) * Cdim;
                const float* plb = xb + (size_t)RL(f + 6) * Cdim;
                const float* prt = xb + (size_t)RL(f + 7) * Cdim;
                float sv = glt * plt[lane] + grb * prb[lane]
                         + glb * plb[lane] + grt * prt[lane];
                acc[i] += wk9[k] * sv;
            }
        }
#undef RL
#undef GV

#pragma unroll
        for (int i = 0; i < 8; ++i) accs[gu * 8 + i][lane] = acc[i];
        __syncthreads();

        // Phase B: lane = pixel; 64->64 pointwise, wave-uniform weights.
        int pix = pix0 + lane;
        int hw  = pix & (HW - 1);

        float s[8];
#pragma unroll
        for (int i = 0; i < 8; ++i) s[i] = 0.f;

        for (int c0 = 0; c0 < Cdim; c0 += 8) {
            float xc[8];
#pragma unroll
            for (int q = 0; q < 8; ++q) xc[q] = accs[lane][c0 + q];
#pragma unroll
            for (int i = 0; i < 8; ++i) {
#pragma unroll
                for (int q = 0; q < 8; ++q)
                    s[i] += c_pw[(gu * 8 + i) * Cdim + c0 + q] * xc[q];
            }
        }

        size_t obase = (size_t)b * Cdim * HW + hw;
#pragma unroll
        for (int i = 0; i < 8; ++i)
            out[obase + (size_t)(gu * 8 + i) * HW] = s[i];

        __syncthreads();   // accs WAR before next tile
    }
}

extern "C" void kernel_launch(void* const* d_in, const int* in_sizes, int n_in,
                              void* d_out, int out_size, void* d_ws, size_t ws_size,
                              hipStream_t stream) {
    const float* x    = (const float*)d_in[0];
    const float* p_dw = (const float*)d_in[1];
    const float* p_pw = (const float*)d_in[2];
    const float* c_dw = (const float*)d_in[3];
    const float* c_pw = (const float*)d_in[4];
    float* out = (float*)d_out;

    float* xt  = (float*)d_ws;                                  // 17.3 MB padded NHWC
    float* geo = (float*)((char*)d_ws + (size_t)4 * HWp * Cdim * 4);  // 18.9 MB

    offset_geo_kernel<<<dim3(NBLK), dim3(512), 0, stream>>>(x, p_dw, p_pw, xt, geo);
    deform_kernel<<<dim3(NBLK2), dim3(512), 0, stream>>>(xt, c_dw, c_pw, (const int*)geo, out);
}

// Round 14
// 63.957 us; speedup vs baseline: 3.9258x; 1.2626x over previous
//
#include <hip/hip_runtime.h>
#include <hip/hip_fp16.h>

#define Hdim 128
#define Wdim 128
#define Cdim 64
#define HW   (Hdim * Wdim)
#define NPIX (4 * HW)     // 65536
#define NBLK (NPIX / 64)  // 1024 blocks / tiles, 64 pixels each
#define NXCD 8
#define Hp 130            // padded dims
#define HWp (Hp * Hp)     // 16900

// XCD-aware bijective swizzle (nwg % 8 == 0): consecutive logical blocks
// (which share image rows -> xt reuse) land on the SAME XCD's L2.
__device__ __forceinline__ int xcd_swizzle(int bid, int nblk) {
    return (bid % NXCD) * (nblk / NXCD) + bid / NXCD;
}

// geo layout: [group = pixel>>3][k:9][i:8 px][8 dwords {w0..w3, i0..i3}]

// ---------------------------------------------------------------------------
// Kernel A: fused {NCHW->padded-NHWC-fp16 transpose} + {offset conv dw3x3 +
// pw 64->18} + {sampling geometry}.  xt is fp16: halves deform's gather
// bytes (the measured L1-fill wall) at negligible precision cost
// (x ~ N(0,1), rel err 4.9e-4 -> ~1e-4 absolute on the output).
// ---------------------------------------------------------------------------
__global__ __launch_bounds__(512) void offset_geo_kernel(
    const float* __restrict__ x,     // (B, C, H, W)
    const float* __restrict__ p_dw,  // (C, 1, 3, 3)
    const float* __restrict__ p_pw,  // (18, C, 1, 1)
    __half* __restrict__ xt,         // (B, 130, 130, C) padded NHWC fp16
    float* __restrict__ geo)         // (8192, 9, 8, 8) dwords
{
    __shared__ float part[8][18][64];   // 36.8 KB; part[0] reused as sum

    int lane = threadIdx.x & 63;
    int g    = threadIdx.x >> 6;
    int blk  = xcd_swizzle(blockIdx.x, NBLK);
    int pix0 = blk * 64;
    int pix  = pix0 + lane;
    int w = pix & (Wdim - 1);
    int h = (pix >> 7) & (Hdim - 1);
    int b = pix >> 14;

    // --- zero the pad ring of xt (2064 ring positions x 128 B) -----------
    {
        int gid = blockIdx.x * 512 + threadIdx.x;   // raw id: blocks 0..32
        if (gid < 2064 * 8) {
            int rp  = gid >> 3, sub = gid & 7;
            int img = rp / 516, pos = rp - img * 516;
            int i, j;
            if (pos < 130)      { i = 0;   j = pos; }
            else if (pos < 260) { i = 129; j = pos - 130; }
            else { int p2 = pos - 260; i = 1 + (p2 >> 1); j = (p2 & 1) ? 129 : 0; }
            float4* dst = (float4*)(xt + ((size_t)img * HWp + i * Hp + j) * Cdim);
            dst[sub] = make_float4(0.f, 0.f, 0.f, 0.f);
        }
    }

    // --- depthwise 3x3: masks/offsets hoisted out of the channel loop ----
    int   off9[9];
    float msk9[9];
#pragma unroll
    for (int dh = -1; dh <= 1; ++dh) {
#pragma unroll
        for (int dw = -1; dw <= 1; ++dw) {
            int tap = (dh + 1) * 3 + (dw + 1);
            int hh = h + dh, ww = w + dw;
            bool ok = (hh >= 0) & (hh < Hdim) & (ww >= 0) & (ww < Wdim);
            off9[tap] = ok ? hh * Wdim + ww : 0;
            msk9[tap] = ok ? 1.f : 0.f;
        }
    }

    float t[8], ctr[8];
#pragma unroll
    for (int i = 0; i < 8; ++i) {
        int c = g * 8 + i;              // wave-uniform
        const float* xb = x + (size_t)(b * Cdim + c) * HW;
        float s = 0.f;
#pragma unroll
        for (int tap = 0; tap < 9; ++tap) {
            float v = xb[off9[tap]] * msk9[tap];
            s += v * p_dw[c * 9 + tap];
        }
        t[i]   = s;
        ctr[i] = xb[h * Wdim + w];      // transpose source (center tap)
    }

    // --- transpose write: 8 channels -> 4x half2 packed in one 16B store --
    {
        __half2 h0 = __floats2half2_rn(ctr[0], ctr[1]);
        __half2 h1 = __floats2half2_rn(ctr[2], ctr[3]);
        __half2 h2 = __floats2half2_rn(ctr[4], ctr[5]);
        __half2 h3 = __floats2half2_rn(ctr[6], ctr[7]);
        uint4 pk;
        pk.x = *(const unsigned int*)&h0;
        pk.y = *(const unsigned int*)&h1;
        pk.z = *(const unsigned int*)&h2;
        pk.w = *(const unsigned int*)&h3;
        size_t ppos = ((size_t)b * HWp + (h + 1) * Hp + (w + 1)) * Cdim + g * 8;
        *(uint4*)(xt + ppos) = pk;      // 16B-aligned (g*8 halves)
    }

    // --- pointwise 64->18 partials -> LDS ---------------------------------
#pragma unroll
    for (int j = 0; j < 18; ++j) {
        float s = 0.f;
#pragma unroll
        for (int i = 0; i < 8; ++i)
            s += p_pw[j * Cdim + g * 8 + i] * t[i];
        part[g][j][lane] = s;
    }
    __syncthreads();

    // reduce 8 partials into part[0]
#pragma unroll
    for (int it = 0; it < 3; ++it) {
        int idx = threadIdx.x + it * 512;
        if (idx < 18 * 64) {
            int j = idx >> 6;
            int p = idx & 63;
            float s = part[0][j][p];
#pragma unroll
            for (int q = 1; q < 8; ++q) s += part[q][j][p];
            part[0][j][p] = s;
        }
    }
    __syncthreads();

    // --- geometry pass: reference formulas verbatim on the padded grid ---
#pragma unroll
    for (int it = 0; it < 2; ++it) {
        int idx = threadIdx.x + it * 512;
        if (idx < 9 * 64) {
            int k = idx >> 6;
            int p = idx & 63;
            int ppix = pix0 + p;
            int pw2 = ppix & (Wdim - 1);
            int ph2 = (ppix >> 7) & (Hdim - 1);

            float px = (float)(ph2 + 1) + (float)(k / 3 - 1) + part[0][k][p];
            float py = (float)(pw2 + 1) + (float)(k % 3 - 1) + part[0][k + 9][p];

            float fx = floorf(px), fy = floorf(py);
            float ltx = fminf(fmaxf(fx, 0.f), 129.f);
            float lty = fminf(fmaxf(fy, 0.f), 129.f);
            float rbx = fminf(fmaxf(fx + 1.f, 0.f), 129.f);
            float rby = fminf(fmaxf(fy + 1.f, 0.f), 129.f);
            float pxc = fminf(fmaxf(px, 0.f), 129.f);
            float pyc = fminf(fmaxf(py, 0.f), 129.f);

            float glt = (1.f + ltx - pxc) * (1.f + lty - pyc);
            float grb = (1.f - rbx + pxc) * (1.f - rby + pyc);
            float glb = (1.f + ltx - pxc) * (1.f - rby + pyc);
            float grt = (1.f - rbx + pxc) * (1.f + lty - pyc);

            int ix0 = (int)ltx, iy0 = (int)lty, ix1 = (int)rbx, iy1 = (int)rby;

            // entry = (group*9 + k)*8 + i   (group = pixel>>3)
            size_t e = (((size_t)blk * 8 + (p >> 3)) * 9 + k) * 8 + (p & 7);
            float4* wdst = (float4*)(geo + e * 8);
            int4*   idst = (int4*)(geo + e * 8 + 4);
            *wdst = make_float4(glt, grb, glb, grt);
            *idst = make_int4(ix0 * Hp + iy0,   // lt
                              ix1 * Hp + iy1,   // rb
                              ix0 * Hp + iy1,   // lb
                              ix1 * Hp + iy0);  // rt
        }
    }
}

// ---------------------------------------------------------------------------
// Kernel B: deformable sampling + collapsed depthwise + pointwise.
// R10 structure (known-good: 1024 blocks x 512 thr, wave-geo readlane
// broadcast, saddr gathers) with fp16 xt: each corner gather = 64 lanes x
// 2 B = 128 B = 2 cache lines (was 4) -> the L1 miss/fill wall halves.
// ---------------------------------------------------------------------------
__global__ __launch_bounds__(512) void deform_kernel(
    const __half* __restrict__ xt,   // (B, 130, 130, C) padded NHWC fp16
    const float* __restrict__ c_dw,  // (C, 1, 3, 3)
    const float* __restrict__ c_pw,  // (C, C, 1, 1)
    const int* __restrict__ geo,     // (8192, 9, 8, 8) dwords
    float* __restrict__ out)         // (B, C, H, W)
{
    __shared__ float accs[64][65];   // [pixel][channel] padded, 16.6 KB

    int lane = threadIdx.x & 63;
    int gu   = __builtin_amdgcn_readfirstlane(threadIdx.x >> 6);
    int blk  = xcd_swizzle(blockIdx.x, NBLK);
    int pix0 = blk * 64;
    int b    = pix0 >> 14;           // block-uniform
    const __half* xb = xt + (size_t)b * HWp * Cdim;

    // prefetch this wave's geometry: 576 dwords -> 9 VGPRs per lane
    int gv0, gv1, gv2, gv3, gv4, gv5, gv6, gv7, gv8;
    {
        const int* gb = geo + ((size_t)blk * 8 + gu) * 576 + lane;
        gv0 = gb[0];   gv1 = gb[64];  gv2 = gb[128];
        gv3 = gb[192]; gv4 = gb[256]; gv5 = gb[320];
        gv6 = gb[384]; gv7 = gb[448]; gv8 = gb[512];
    }
    // per-lane depthwise weights (lane = channel)
    float wk9[9];
#pragma unroll
    for (int k = 0; k < 9; ++k) wk9[k] = c_dw[lane * 9 + k];

#define GV(r) ((r)==0?gv0:(r)==1?gv1:(r)==2?gv2:(r)==3?gv3:(r)==4?gv4: \
               (r)==5?gv5:(r)==6?gv6:(r)==7?gv7:gv8)
#define RL(f) __builtin_amdgcn_readlane(GV((f) >> 6), (f) & 63)

    float acc[8];
#pragma unroll
    for (int i = 0; i < 8; ++i) acc[i] = 0.f;

#pragma unroll
    for (int k = 0; k < 9; ++k) {
#pragma unroll
        for (int i = 0; i < 8; ++i) {
            const int f = (k * 8 + i) * 8;
            float glt = __int_as_float(RL(f + 0));
            float grb = __int_as_float(RL(f + 1));
            float glb = __int_as_float(RL(f + 2));
            float grt = __int_as_float(RL(f + 3));
            const __half* plt = xb + (size_t)RL(f + 4) * Cdim;
            const __half* prb = xb + (size_t)RL(f + 5) * Cdim;
            const __half* plb = xb + (size_t)RL(f + 6) * Cdim;
            const __half* prt = xb + (size_t)RL(f + 7) * Cdim;
            float sv = glt * __half2float(plt[lane])
                     + grb * __half2float(prb[lane])
                     + glb * __half2float(plb[lane])
                     + grt * __half2float(prt[lane]);
            acc[i] += wk9[k] * sv;
        }
    }
#undef RL
#undef GV

#pragma unroll
    for (int i = 0; i < 8; ++i) accs[gu * 8 + i][lane] = acc[i];
    __syncthreads();

    // Phase B: lane = pixel; 64->64 pointwise, wave-uniform weights.
    int pix = pix0 + lane;
    int hw  = pix & (HW - 1);

    float s[8];
#pragma unroll
    for (int i = 0; i < 8; ++i) s[i] = 0.f;

    for (int c0 = 0; c0 < Cdim; c0 += 8) {
        float xc[8];
#pragma unroll
        for (int q = 0; q < 8; ++q) xc[q] = accs[lane][c0 + q];
#pragma unroll
        for (int i = 0; i < 8; ++i) {
#pragma unroll
            for (int q = 0; q < 8; ++q)
                s[i] += c_pw[(gu * 8 + i) * Cdim + c0 + q] * xc[q];
        }
    }

    size_t obase = (size_t)b * Cdim * HW + hw;
#pragma unroll
    for (int i = 0; i < 8; ++i)
        out[obase + (size_t)(gu * 8 + i) * HW] = s[i];
}

extern "C" void kernel_launch(void* const* d_in, const int* in_sizes, int n_in,
                              void* d_out, int out_size, void* d_ws, size_t ws_size,
                              hipStream_t stream) {
    const float* x    = (const float*)d_in[0];
    const float* p_dw = (const float*)d_in[1];
    const float* p_pw = (const float*)d_in[2];
    const float* c_dw = (const float*)d_in[3];
    const float* c_pw = (const float*)d_in[4];
    float* out = (float*)d_out;

    __half* xt = (__half*)d_ws;                                 // 8.65 MB padded NHWC fp16
    float* geo = (float*)((char*)d_ws + (size_t)4 * HWp * Cdim * 2);  // 18.9 MB

    offset_geo_kernel<<<dim3(NBLK), dim3(512), 0, stream>>>(x, p_dw, p_pw, xt, geo);
    deform_kernel<<<dim3(NBLK), dim3(512), 0, stream>>>(xt, c_dw, c_pw, (const int*)geo, out);
}